// Round 9
// baseline (111.046 us; speedup 1.0000x reference)
//
#include <hip/hip_runtime.h>

// Problem constants (fixed by setup_inputs in the reference)
#define B_  8
#define T_  2048
#define D_  1024
#define H_  8
#define S_  128

// --------------------------------------------------------------------------
// K1: logits[row][h] = dot(feat[row,:], kw[h,:]) + kb[h]  — with span-
// coverage gating. One row per wave, 1024-thread blocks, kw staged into
// 32 KB LDS, 32 waves/CU, one HBM stop per wave (R7 structure).
// NEW (R9): each wave first checks whether ANY span of its batch covers its
// row t (2 spans/lane x 64 lanes = all 128 spans; two coalesced int2 loads
// from L2; __ballot reduce). ~65% of rows are covered -> ~35% of the 64 MB
// feat stream is skipped (feat load + FMAs + logit store). Uncovered rows'
// logit slots keep ws poison; K2 masks those slots by SELECTION (?:) before
// any arithmetic, so poison is never consumed.
// --------------------------------------------------------------------------
__global__ __launch_bounds__(1024) void logits_kernel(
    const float* __restrict__ feat,    // [B*T, D]
    const int* __restrict__ begins,    // [B*S]
    const int* __restrict__ ends,      // [B*S]
    const float* __restrict__ kw,      // [H, D]
    const float* __restrict__ kb,      // [H]
    float* __restrict__ logits)        // [B*T, H]
{
    const int wv   = threadIdx.x >> 6;      // 0..15
    const int lane = threadIdx.x & 63;
    const int row  = blockIdx.x * 16 + wv;  // 1024 blocks -> rows 0..16383

    __shared__ __align__(16) float kwl[H_ * D_];  // 32 KB staged key_w

    {   // stage kw: 1024 threads x 2 float4 (coalesced)
        const float4* src = (const float4*)kw;
        float4*       dst = (float4*)kwl;
        dst[threadIdx.x]        = src[threadIdx.x];
        dst[threadIdx.x + 1024] = src[threadIdx.x + 1024];
    }

    // ---- coverage test: does any span of batch b contain t? (wave-uniform)
    const int b = row >> 11;                // / T_
    const int t = row & (T_ - 1);
    const int2 bg = *(const int2*)(begins + b * S_ + 2 * lane);
    const int2 en = *(const int2*)(ends   + b * S_ + 2 * lane);
    const bool cov = (bg.x <= t && t < en.x) || (bg.y <= t && t < en.y);
    const bool do_row = (__ballot(cov) != 0ull);

    // Row loads issued BEFORE the barrier (independent of LDS staging).
    float4 fv0, fv1, fv2, fv3;
    if (do_row) {
        const float* fr = feat + (size_t)row * D_;
        fv0 = *(const float4*)(fr +   0 + lane * 4);
        fv1 = *(const float4*)(fr + 256 + lane * 4);
        fv2 = *(const float4*)(fr + 512 + lane * 4);
        fv3 = *(const float4*)(fr + 768 + lane * 4);
    }

    __syncthreads();

    if (!do_row) return;                    // after barrier: safe

    float acc[H_];
#pragma unroll
    for (int h = 0; h < H_; ++h) {
        const float* kh = &kwl[h * D_ + lane * 4];
        float4 k0 = *(const float4*)(kh +   0);
        float4 k1 = *(const float4*)(kh + 256);
        float4 k2 = *(const float4*)(kh + 512);
        float4 k3 = *(const float4*)(kh + 768);
        acc[h] = fv0.x * k0.x + fv0.y * k0.y + fv0.z * k0.z + fv0.w * k0.w
               + fv1.x * k1.x + fv1.y * k1.y + fv1.z * k1.z + fv1.w * k1.w
               + fv2.x * k2.x + fv2.y * k2.y + fv2.z * k2.z + fv2.w * k2.w
               + fv3.x * k3.x + fv3.y * k3.y + fv3.z * k3.z + fv3.w * k3.w;
    }

    // Value-compacting reduce over lane bits 0..2 (4+2+1 = 7 shuffles)
#pragma unroll
    for (int s = 0; s < 3; ++s) {
        const int m = 1 << s;
        const bool hi = (lane >> s) & 1;
#pragma unroll
        for (int j = 0; j < (4 >> s); ++j) {
            float mine  = hi ? acc[2 * j + 1] : acc[2 * j];
            float other = hi ? acc[2 * j]     : acc[2 * j + 1];
            acc[j] = mine + __shfl_xor(other, m, 64);
        }
    }
    acc[0] += __shfl_xor(acc[0],  8, 64);
    acc[0] += __shfl_xor(acc[0], 16, 64);
    acc[0] += __shfl_xor(acc[0], 32, 64);

    if (lane < H_)
        logits[(size_t)row * H_ + lane] = acc[0] + kb[lane];
}

// --------------------------------------------------------------------------
// K2 (frozen from R8): one block per (span, quarter-of-D). 4096 blocks x
// 256 threads -> 8 blocks/CU, 32 waves/CU. Wave w's 8 independent span-row
// float4 loads issue before the barrier; wave 0 concurrently computes the
// register softmax (t >= width*8 masked to -1e30 BY SELECTION -> weight
// exactly 0; poison-safe) and drops 256 weights into LDS; weights then read
// as conflict-free half-wave broadcasts; partials reduce through LDS.
// Rows begin..begin+31 always in-bounds (begin <= 2015).
// --------------------------------------------------------------------------
__global__ __launch_bounds__(256) void pool_kernel(
    const float* __restrict__ feat,    // [B*T, D]
    const int* __restrict__ begins,    // [B*S]
    const int* __restrict__ ends,      // [B*S]
    const float* __restrict__ logits,  // [B*T, H]
    float* __restrict__ out)           // [B*S, D]
{
    const int blk  = blockIdx.x;            // bs*4 + q
    const int bs   = blk >> 2;
    const int q    = blk & 3;
    const int wv   = threadIdx.x >> 6;      // row-chunk 0..3
    const int lane = threadIdx.x & 63;
    const int b    = bs >> 7;               // / S_

    const int begin = begins[bs];
    const int width = ends[bs] - begin;     // 1..32
    const size_t row0 = (size_t)b * T_ + begin;

    __shared__ __align__(16) float wslab[256];        // weights [i*8+h]
    __shared__ __align__(16) float pslab[4 * 256];    // per-wave partials

    const int colbase = q * 256 + lane * 4;
    const float* fbase = feat + row0 * D_ + colbase;
    const bool active = (wv * 8) < width;
    float4 fv[8];
    if (active) {
#pragma unroll
        for (int k = 0; k < 8; ++k)
            fv[k] = *(const float4*)(fbase + (size_t)(wv * 8 + k) * D_);
    }

    if (wv == 0) {
        float4 lv = *(const float4*)(logits + row0 * H_ + lane * 4);
        const int w8 = width * H_;
        float v0 = (4 * lane + 0 < w8) ? lv.x : -1e30f;
        float v1 = (4 * lane + 1 < w8) ? lv.y : -1e30f;
        float v2 = (4 * lane + 2 < w8) ? lv.z : -1e30f;
        float v3 = (4 * lane + 3 < w8) ? lv.w : -1e30f;

        float m0 = v0, m1 = v1, m2 = v2, m3 = v3;
#pragma unroll
        for (int off = 2; off <= 32; off <<= 1) {
            m0 = fmaxf(m0, __shfl_xor(m0, off, 64));
            m1 = fmaxf(m1, __shfl_xor(m1, off, 64));
            m2 = fmaxf(m2, __shfl_xor(m2, off, 64));
            m3 = fmaxf(m3, __shfl_xor(m3, off, 64));
        }
        float e0 = __expf(v0 - m0);          // masked -> exactly 0
        float e1 = __expf(v1 - m1);
        float e2 = __expf(v2 - m2);
        float e3 = __expf(v3 - m3);
        float s0 = e0, s1 = e1, s2 = e2, s3 = e3;
#pragma unroll
        for (int off = 2; off <= 32; off <<= 1) {
            s0 += __shfl_xor(s0, off, 64);
            s1 += __shfl_xor(s1, off, 64);
            s2 += __shfl_xor(s2, off, 64);
            s3 += __shfl_xor(s3, off, 64);
        }
        *(float4*)&wslab[lane * 4] =
            make_float4(e0 / s0, e1 / s1, e2 / s2, e3 / s3);
    }
    __syncthreads();

    float4 acc = make_float4(0.f, 0.f, 0.f, 0.f);
    if (active) {
        const int hoff = 2 * q + (lane >= 32 ? 1 : 0);  // head for my cols
#pragma unroll
        for (int k = 0; k < 8; ++k) {
            const float wt = wslab[(wv * 8 + k) * 8 + hoff];
            acc.x += wt * fv[k].x;
            acc.y += wt * fv[k].y;
            acc.z += wt * fv[k].z;
            acc.w += wt * fv[k].w;
        }
    }
    *(float4*)&pslab[wv * 256 + lane * 4] = acc;   // inactive waves write 0
    __syncthreads();

    if (wv == 0) {
        float4 r0 = *(const float4*)&pslab[0 * 256 + lane * 4];
        float4 r1 = *(const float4*)&pslab[1 * 256 + lane * 4];
        float4 r2 = *(const float4*)&pslab[2 * 256 + lane * 4];
        float4 r3 = *(const float4*)&pslab[3 * 256 + lane * 4];
        float4 o = make_float4(r0.x + r1.x + r2.x + r3.x,
                               r0.y + r1.y + r2.y + r3.y,
                               r0.z + r1.z + r2.z + r3.z,
                               r0.w + r1.w + r2.w + r3.w);
        *(float4*)(out + (size_t)bs * D_ + colbase) = o;
    }
}

extern "C" void kernel_launch(void* const* d_in, const int* in_sizes, int n_in,
                              void* d_out, int out_size, void* d_ws, size_t ws_size,
                              hipStream_t stream) {
    const float* feat   = (const float*)d_in[0];   // features f32 [B,T,D]
    const int*   begins = (const int*)d_in[1];     // int32 [B,S]
    const int*   ends   = (const int*)d_in[2];     // int32 [B,S]
    const float* kw     = (const float*)d_in[3];   // key_w f32 [H,D]
    const float* kb     = (const float*)d_in[4];   // key_b f32 [H]
    float*       out    = (float*)d_out;           // f32 [B*S, D]
    float* logits = (float*)d_ws;                  // 16384*8*4 = 512 KB scratch

    logits_kernel<<<1024, 1024, 0, stream>>>(feat, begins, ends, kw, kb, logits);
    pool_kernel<<<B_ * S_ * 4, 256, 0, stream>>>(feat, begins, ends, logits, out);
}